// Round 1
// baseline (1986.922 us; speedup 1.0000x reference)
//
#include <hip/hip_runtime.h>
#include <hip/hip_fp16.h>

#define NDIM  4096
#define LSTEPS 50
#define ANUM   4
#define NMATS  5   // T_base + 4 A_mats

// ---------------------------------------------------------------------------
// init: out[] = 0; x1 = b; out[0] = r . b   (step 0 of the scan: x0 == 0)
// single block of 256 threads
// ---------------------------------------------------------------------------
__global__ void init_kernel(const float* __restrict__ b, const float* __restrict__ r,
                            float* __restrict__ x1, float* __restrict__ out) {
    const int tid = threadIdx.x;
    if (tid < LSTEPS) out[tid] = 0.0f;   // out[0] overwritten below (thread 0 only)
    float part = 0.0f;
    for (int i = tid; i < NDIM; i += 256) {
        float bi = b[i];
        x1[i] = bi;
        part += r[i] * bi;
    }
#pragma unroll
    for (int off = 32; off > 0; off >>= 1) part += __shfl_xor(part, off, 64);
    __shared__ float sm[4];
    const int wave = tid >> 6, lane = tid & 63;
    if (lane == 0) sm[wave] = part;
    __syncthreads();
    if (tid == 0) out[0] = sm[0] + sm[1] + sm[2] + sm[3];
}

// ---------------------------------------------------------------------------
// fp32 -> fp16 conversion of [T_base | A_mats] into workspace.
// Each thread converts 8 elements (two float4 in, one uint4 of 8 halves out).
// Grid sized exactly: NMATS*N*N/8 threads.
// ---------------------------------------------------------------------------
__global__ void conv_kernel(const float* __restrict__ Tb, const float* __restrict__ Am,
                            uint4* __restrict__ dst) {
    const size_t idx  = (size_t)blockIdx.x * 256 + threadIdx.x;
    const size_t base = idx * 8;
    const size_t nn   = (size_t)NDIM * NDIM;
    const float4* src;
    size_t off4;
    if (base < nn) { src = (const float4*)Tb; off4 = base >> 2; }
    else           { src = (const float4*)Am; off4 = (base - nn) >> 2; }
    const float4 f0 = src[off4];
    const float4 f1 = src[off4 + 1];
    union { uint4 v; __half h[8]; } pk;
    pk.h[0] = __float2half(f0.x); pk.h[1] = __float2half(f0.y);
    pk.h[2] = __float2half(f0.z); pk.h[3] = __float2half(f0.w);
    pk.h[4] = __float2half(f1.x); pk.h[5] = __float2half(f1.y);
    pk.h[6] = __float2half(f1.z); pk.h[7] = __float2half(f1.w);
    dst[idx] = pk.v;
}

// ---------------------------------------------------------------------------
// One recurrence step, fp16 matrices:
//   y = T_base@x + sum_a act[a]*(A_a@x) + b ;  x_out = y ;  out[t] += r.y
// 1024 blocks x 256 threads; one wave per output row (4 rows/block).
// x (16 KB fp32) staged in LDS; 5 accumulators combined with act BEFORE the
// wave reduction (linearity) so only one 6-stage shuffle tree per row.
// ---------------------------------------------------------------------------
__global__ __launch_bounds__(256) void step_half(
        const uint4* __restrict__ mats,   // [NMATS][N][N] halves, 8/uint4
        const float* __restrict__ x_in,
        float*       __restrict__ x_out,
        const float* __restrict__ b,
        const float* __restrict__ r,
        const float* __restrict__ traj,
        float*       __restrict__ out, int t) {
    __shared__ float xs[NDIM];
    __shared__ float parts[4];
    const int tid = threadIdx.x;
    {
        const float4* xv  = (const float4*)x_in;
        float4*       xsv = (float4*)xs;
#pragma unroll
        for (int i = 0; i < 4; i++) xsv[tid + 256 * i] = xv[tid + 256 * i];
    }
    __syncthreads();

    const float a0 = traj[t * ANUM + 0], a1 = traj[t * ANUM + 1],
                a2 = traj[t * ANUM + 2], a3 = traj[t * ANUM + 3];

    const int wave = tid >> 6, lane = tid & 63;
    const int row  = blockIdx.x * 4 + wave;
    const size_t matq = (size_t)NDIM * NDIM / 8;   // uint4 per matrix
    const size_t rowq = (size_t)row * (NDIM / 8);  // uint4 per row

    float acc[NMATS] = {0.f, 0.f, 0.f, 0.f, 0.f};
#pragma unroll
    for (int c = 0; c < 8; c++) {
        const float4* xp = (const float4*)(&xs[c * 512 + lane * 8]);
        const float4 xa = xp[0], xb = xp[1];
        const size_t qi = rowq + (size_t)c * 64 + lane;
#pragma unroll
        for (int m = 0; m < NMATS; m++) {
            union { uint4 v; __half2 h2[4]; } u;
            u.v = mats[(size_t)m * matq + qi];
            const float2 p0 = __half22float2(u.h2[0]);
            const float2 p1 = __half22float2(u.h2[1]);
            const float2 p2 = __half22float2(u.h2[2]);
            const float2 p3 = __half22float2(u.h2[3]);
            float a = acc[m];
            a = fmaf(p0.x, xa.x, a); a = fmaf(p0.y, xa.y, a);
            a = fmaf(p1.x, xa.z, a); a = fmaf(p1.y, xa.w, a);
            a = fmaf(p2.x, xb.x, a); a = fmaf(p2.y, xb.y, a);
            a = fmaf(p3.x, xb.z, a); a = fmaf(p3.y, xb.w, a);
            acc[m] = a;
        }
    }
    float s = acc[0] + a0 * acc[1] + a1 * acc[2] + a2 * acc[3] + a3 * acc[4];
#pragma unroll
    for (int off = 32; off > 0; off >>= 1) s += __shfl_xor(s, off, 64);
    if (lane == 0) {
        const float y = s + b[row];
        x_out[row] = y;
        parts[wave] = r[row] * y;
    }
    __syncthreads();
    if (tid == 0) atomicAdd(out + t, parts[0] + parts[1] + parts[2] + parts[3]);
}

// ---------------------------------------------------------------------------
// Fallback: same step but reading the original fp32 matrices (used only if
// ws_size can't hold the fp16 copies). 2x the HBM traffic of step_half.
// ---------------------------------------------------------------------------
__global__ __launch_bounds__(256) void step_f32(
        const float* __restrict__ Tb, const float* __restrict__ Am,
        const float* __restrict__ x_in, float* __restrict__ x_out,
        const float* __restrict__ b, const float* __restrict__ r,
        const float* __restrict__ traj, float* __restrict__ out, int t) {
    __shared__ float xs[NDIM];
    __shared__ float parts[4];
    const int tid = threadIdx.x;
    {
        const float4* xv  = (const float4*)x_in;
        float4*       xsv = (float4*)xs;
#pragma unroll
        for (int i = 0; i < 4; i++) xsv[tid + 256 * i] = xv[tid + 256 * i];
    }
    __syncthreads();

    const float a0 = traj[t * ANUM + 0], a1 = traj[t * ANUM + 1],
                a2 = traj[t * ANUM + 2], a3 = traj[t * ANUM + 3];

    const int wave = tid >> 6, lane = tid & 63;
    const int row  = blockIdx.x * 4 + wave;
    const size_t nn = (size_t)NDIM * NDIM;
    const float4* mat[NMATS] = {
        (const float4*)Tb, (const float4*)Am, (const float4*)(Am + nn),
        (const float4*)(Am + 2 * nn), (const float4*)(Am + 3 * nn)};
    const size_t rowq = (size_t)row * (NDIM / 4);

    float acc[NMATS] = {0.f, 0.f, 0.f, 0.f, 0.f};
#pragma unroll
    for (int c = 0; c < 16; c++) {
        const float4 xa = *(const float4*)(&xs[c * 256 + lane * 4]);
        const size_t qi = rowq + (size_t)c * 64 + lane;
#pragma unroll
        for (int m = 0; m < NMATS; m++) {
            const float4 v = mat[m][qi];
            float a = acc[m];
            a = fmaf(v.x, xa.x, a); a = fmaf(v.y, xa.y, a);
            a = fmaf(v.z, xa.z, a); a = fmaf(v.w, xa.w, a);
            acc[m] = a;
        }
    }
    float s = acc[0] + a0 * acc[1] + a1 * acc[2] + a2 * acc[3] + a3 * acc[4];
#pragma unroll
    for (int off = 32; off > 0; off >>= 1) s += __shfl_xor(s, off, 64);
    if (lane == 0) {
        const float y = s + b[row];
        x_out[row] = y;
        parts[wave] = r[row] * y;
    }
    __syncthreads();
    if (tid == 0) atomicAdd(out + t, parts[0] + parts[1] + parts[2] + parts[3]);
}

// ---------------------------------------------------------------------------
extern "C" void kernel_launch(void* const* d_in, const int* in_sizes, int n_in,
                              void* d_out, int out_size, void* d_ws, size_t ws_size,
                              hipStream_t stream) {
    // inputs per setup_inputs(): init_states(N) [unused], trajectories(L*ANUM),
    // T_base(N*N), A_mats(ANUM*N*N), b(N), r(N)
    const float* traj = (const float*)d_in[1];
    const float* Tb   = (const float*)d_in[2];
    const float* Am   = (const float*)d_in[3];
    const float* b    = (const float*)d_in[4];
    const float* r    = (const float*)d_in[5];
    float* out = (float*)d_out;

    const size_t matBytes = (size_t)NMATS * NDIM * NDIM * sizeof(__half); // 160 MiB
    const size_t xBytes   = 2 * (size_t)NDIM * sizeof(float);
    const bool useHalf = ws_size >= matBytes + xBytes;

    if (useHalf) {
        uint4* mats = (uint4*)d_ws;
        float* x0 = (float*)((char*)d_ws + matBytes);
        float* x1 = x0 + NDIM;
        init_kernel<<<1, 256, 0, stream>>>(b, r, x0, out);
        const int convBlocks = (int)(((size_t)NMATS * NDIM * NDIM / 8) / 256); // 40960
        conv_kernel<<<convBlocks, 256, 0, stream>>>(Tb, Am, mats);
        for (int t = 1; t < LSTEPS; t++) {
            float* xi = (t & 1) ? x0 : x1;
            float* xo = (t & 1) ? x1 : x0;
            step_half<<<NDIM / 4, 256, 0, stream>>>(mats, xi, xo, b, r, traj, out, t);
        }
    } else {
        float* x0 = (float*)d_ws;
        float* x1 = x0 + NDIM;
        init_kernel<<<1, 256, 0, stream>>>(b, r, x0, out);
        for (int t = 1; t < LSTEPS; t++) {
            float* xi = (t & 1) ? x0 : x1;
            float* xo = (t & 1) ? x1 : x0;
            step_f32<<<NDIM / 4, 256, 0, stream>>>(Tb, Am, xi, xo, b, r, traj, out, t);
        }
    }
}